// Round 6
// baseline (91.420 us; speedup 1.0000x reference)
//
#include <hip/hip_runtime.h>
#include <hip/hip_cooperative_groups.h>
#include <math.h>

namespace cg = cooperative_groups;

// Single-sweep SWALP global block-quantize (cooperative, occupancy-gated):
//   phase 1: stream x once; quantize online to packed int8 vs a running
//            per-thread exponent (int8 per 4-elem chunk); track max|x|.
//   grid.sync(); reduce global exponent e_g
//   phase 2: out = clamp(rne(j*2^(e_c-e_g)))*2^(e_g-6) straight from registers.
//   HBM traffic = 1 read + 1 write = 411 MB (two-pass moves 616 MB).
//   Error bound: double-rounding costs <= 1 output quantum = 2^(e_g-6).
// Fallback (occupancy gate fails / launch error): proven R4 two-pass kernels.

#define NBLK 512
#define NTHR 256
#define NTHREADS (NBLK * NTHR)   // 131072
#define CHUNKS 98                // 131072 * 98 float4 = 51,380,224 floats = n
#define GRID1 2048               // fallback grid

typedef float v4f __attribute__((ext_vector_type(4)));

__device__ inline void store_stream(v4f* p, v4f v) {
    asm volatile("global_store_dwordx4 %0, %1, off sc0 sc1 nt" :: "v"(p), "v"(v));
}

__global__ __launch_bounds__(NTHR, 2) void bq_fused(const float* __restrict__ x,
                                                    float* __restrict__ out,
                                                    float* __restrict__ partial) {
    const int gtid = blockIdx.x * NTHR + threadIdx.x;
    const v4f* __restrict__ x4 = (const v4f*)x;
    v4f* __restrict__ o4 = (v4f*)out;

    unsigned int pj[CHUNKS];            // 4 x int8 quantized vals per chunk
    unsigned int pe[(CHUNKS + 3) / 4];  // 4 x int8 chunk exponents per word

    float m_run = 0.0f;
    int   e_run = -32768;
    float s_run = 0.0f;   // 2^(6-e_run); 0 while all inputs so far are 0 -> j=0

    // ---- phase 1: read once, quantize online, stash in registers ----
    #pragma unroll
    for (int c = 0; c < CHUNKS; ++c) {
        const int i4 = c * NTHREADS + gtid;   // exact coverage, no guard
        v4f v = x4[i4];
        float a = fmaxf(fmaxf(fabsf(v.x), fabsf(v.y)),
                        fmaxf(fabsf(v.z), fabsf(v.w)));
        if (a > m_run) {
            m_run = a;
            int en = ilogbf(a);
            if (en < -120) en = -120;   // floor so e fits int8; error <= 1 quantum
            if (en > e_run) { e_run = en; s_run = ldexpf(1.0f, 6 - e_run); }
        }
        int j0 = (int)rintf(v.x * s_run);
        int j1 = (int)rintf(v.y * s_run);
        int j2 = (int)rintf(v.z * s_run);
        int j3 = (int)rintf(v.w * s_run);
        j0 = min(127, max(-128, j0));
        j1 = min(127, max(-128, j1));
        j2 = min(127, max(-128, j2));
        j3 = min(127, max(-128, j3));
        pj[c] = (unsigned)(j0 & 0xff)         | ((unsigned)(j1 & 0xff) << 8) |
                ((unsigned)(j2 & 0xff) << 16) | ((unsigned)(j3 & 0xff) << 24);
        const unsigned eb = (unsigned)(e_run & 0xff);
        const int sh = (c & 3) * 8;
        if ((c & 3) == 0) pe[c >> 2] = eb;
        else              pe[c >> 2] |= eb << sh;
    }

    // ---- block reduce max -> partial[blockIdx] ----
    float bm = m_run;
    #pragma unroll
    for (int off = 32; off > 0; off >>= 1)
        bm = fmaxf(bm, __shfl_xor(bm, off, 64));
    __shared__ float sm[4];
    if ((threadIdx.x & 63) == 0) sm[threadIdx.x >> 6] = bm;
    __syncthreads();
    if (threadIdx.x == 0)
        partial[blockIdx.x] = fmaxf(fmaxf(sm[0], sm[1]), fmaxf(sm[2], sm[3]));

    cg::this_grid().sync();

    // ---- global reduce (redundant per block; NBLK floats, L2-hit) ----
    float gm = 0.0f;
    #pragma unroll
    for (int k = 0; k < NBLK / NTHR; ++k)
        gm = fmaxf(gm, partial[threadIdx.x + k * NTHR]);
    #pragma unroll
    for (int off = 32; off > 0; off >>= 1)
        gm = fmaxf(gm, __shfl_xor(gm, off, 64));
    if ((threadIdx.x & 63) == 0) sm[threadIdx.x >> 6] = gm;
    __syncthreads();
    const float maxe = fmaxf(fmaxf(sm[0], sm[1]), fmaxf(sm[2], sm[3]));

    int e_g = 0;
    if (maxe != 0.0f) {
        e_g = ilogbf(maxe);
        e_g = max(-128, min(127, e_g));
    }
    const float invs = ldexpf(1.0f, e_g - 6);

    // ---- phase 2: emit from registers, streaming stores ----
    #pragma unroll
    for (int c = 0; c < CHUNKS; ++c) {
        const int i4 = c * NTHREADS + gtid;
        const int ec = (int)(signed char)((pe[c >> 2] >> ((c & 3) * 8)) & 0xffu);
        const float fs = ldexpf(1.0f, ec - e_g);  // <= 1, exact pow2
        const unsigned w = pj[c];
        float f0 = (float)(int)(signed char)(w & 0xff);
        float f1 = (float)(int)(signed char)((w >> 8) & 0xff);
        float f2 = (float)(int)(signed char)((w >> 16) & 0xff);
        float f3 = (float)(int)(signed char)((w >> 24) & 0xff);
        f0 = fminf(fmaxf(rintf(f0 * fs), -128.0f), 127.0f);
        f1 = fminf(fmaxf(rintf(f1 * fs), -128.0f), 127.0f);
        f2 = fminf(fmaxf(rintf(f2 * fs), -128.0f), 127.0f);
        f3 = fminf(fmaxf(rintf(f3 * fs), -128.0f), 127.0f);
        v4f r;
        r.x = f0 * invs;
        r.y = f1 * invs;
        r.z = f2 * invs;
        r.w = f3 * invs;
        store_stream(&o4[i4], r);
    }
}

// ---------------- fallback: proven R4 two-pass ----------------

__global__ __launch_bounds__(256) void bq_absmax(const float* __restrict__ x,
                                                 float* __restrict__ partial,
                                                 int n) {
    const int n4 = n >> 2;
    const v4f* __restrict__ x4 = (const v4f*)x;
    int tid = blockIdx.x * blockDim.x + threadIdx.x;
    int stride = gridDim.x * blockDim.x;
    float m = 0.0f;
    for (int i = tid; i < n4; i += stride) {
        v4f v = x4[i];
        m = fmaxf(fmaxf(fabsf(v.x), fabsf(v.y)),
                  fmaxf(fmaxf(fabsf(v.z), fabsf(v.w)), m));
    }
    for (int i = (n4 << 2) + tid; i < n; i += stride) m = fmaxf(m, fabsf(x[i]));
    #pragma unroll
    for (int off = 32; off > 0; off >>= 1)
        m = fmaxf(m, __shfl_xor(m, off, 64));
    __shared__ float sm[4];
    if ((threadIdx.x & 63) == 0) sm[threadIdx.x >> 6] = m;
    __syncthreads();
    if (threadIdx.x == 0)
        partial[blockIdx.x] = fmaxf(fmaxf(sm[0], sm[1]), fmaxf(sm[2], sm[3]));
}

__global__ __launch_bounds__(256) void bq_quant(const float* __restrict__ x,
                                                float* __restrict__ out,
                                                const float* __restrict__ partial,
                                                int n) {
    float bm = 0.0f;
    #pragma unroll
    for (int k = 0; k < GRID1 / 256; ++k)
        bm = fmaxf(bm, partial[threadIdx.x + k * 256]);
    #pragma unroll
    for (int off = 32; off > 0; off >>= 1)
        bm = fmaxf(bm, __shfl_xor(bm, off, 64));
    __shared__ float sm[4];
    if ((threadIdx.x & 63) == 0) sm[threadIdx.x >> 6] = bm;
    __syncthreads();
    const float maxe = fmaxf(fmaxf(sm[0], sm[1]), fmaxf(sm[2], sm[3]));

    const int n4 = n >> 2;
    const v4f* __restrict__ x4 = (const v4f*)x;
    v4f* __restrict__ o4 = (v4f*)out;
    const int tid = blockIdx.x * blockDim.x + threadIdx.x;
    const int T = gridDim.x * blockDim.x;
    const int C = (n4 + T - 1) / T;

    if (maxe == 0.0f) {
        for (int c = C - 1; c >= 0; --c) {
            int i = c * T + tid;
            if (i < n4) store_stream(&o4[i], x4[i]);
        }
        for (int i = (n4 << 2) + tid; i < n; i += T) out[i] = x[i];
        return;
    }

    int e = ilogbf(maxe);
    e = max(-128, min(127, e));
    const float scale    = ldexpf(1.0f, -e + 6);
    const float invscale = ldexpf(1.0f, e - 6);

    for (int c = C - 1; c >= 0; --c) {
        int i = c * T + tid;
        if (i < n4) {
            v4f v = x4[i];
            float a = rintf(v.x * scale);
            float b = rintf(v.y * scale);
            float cc = rintf(v.z * scale);
            float d = rintf(v.w * scale);
            a  = fminf(fmaxf(a,  -128.0f), 127.0f);
            b  = fminf(fmaxf(b,  -128.0f), 127.0f);
            cc = fminf(fmaxf(cc, -128.0f), 127.0f);
            d  = fminf(fmaxf(d,  -128.0f), 127.0f);
            v4f r;
            r.x = a * invscale;
            r.y = b * invscale;
            r.z = cc * invscale;
            r.w = d * invscale;
            store_stream(&o4[i], r);
        }
    }
    for (int i = (n4 << 2) + tid; i < n; i += T) {
        float a = rintf(x[i] * scale);
        a = fminf(fmaxf(a, -128.0f), 127.0f);
        out[i] = a * invscale;
    }
}

extern "C" void kernel_launch(void* const* d_in, const int* in_sizes, int n_in,
                              void* d_out, int out_size, void* d_ws, size_t ws_size,
                              hipStream_t stream) {
    const float* x = (const float*)d_in[0];
    float* out = (float*)d_out;
    float* partial = (float*)d_ws;  // >= GRID1 floats
    int n = in_sizes[0];

    // Occupancy-gated cooperative path (host queries: capture-safe, deterministic)
    bool coop = (n == NTHREADS * CHUNKS * 4);
    if (coop) {
        int nb = 0;
        if (hipOccupancyMaxActiveBlocksPerMultiprocessor(&nb, (const void*)bq_fused,
                                                         NTHR, 0) == hipSuccess) {
            int dev = 0, ncu = 0;
            hipGetDevice(&dev);
            hipDeviceGetAttribute(&ncu, hipDeviceAttributeMultiprocessorCount, dev);
            coop = (nb > 0) && ((long)nb * ncu >= NBLK);
        } else {
            coop = false;
        }
    }
    if (coop) {
        void* args[] = {(void*)&x, (void*)&out, (void*)&partial};
        coop = hipLaunchCooperativeKernel((const void*)bq_fused, dim3(NBLK),
                                          dim3(NTHR), args, 0, stream) == hipSuccess;
    }
    if (!coop) {
        hipLaunchKernelGGL(bq_absmax, dim3(GRID1), dim3(256), 0, stream, x, partial, n);
        hipLaunchKernelGGL(bq_quant,  dim3(GRID1), dim3(256), 0, stream, x, out, partial, n);
    }
}

// Round 7
// 90.258 us; speedup vs baseline: 1.0129x; 1.0129x over previous
//
#include <hip/hip_runtime.h>
#include <math.h>

// SWALP global block-quantize via compressed int8 intermediate in d_ws:
//   k1: per-float4 group: e_c = floor(log2 max|v|) (bit-extract, floored at
//       -120), j = clamp(rne(v * 2^(6-e_c))) -> packed dword + int8 exponent.
//       Also per-block absmax -> partial[blockIdx].
//   k2: reduce partials -> e_g; out = rne(j * 2^(e_c-e_g)) * 2^(e_g-6).
//       j*2^(e_c-e_g) is exact (8-bit int x pow2), so error <= 1 quantum.
// Traffic: 205R + 64W + 64R + 205W = 538 MB (two-pass = 616 MB).
// Fallback if ws too small: proven R4 two-pass (90.5 us).

#define GRID1 2048

typedef float v4f __attribute__((ext_vector_type(4)));

__device__ inline void store_stream(v4f* p, v4f v) {
    asm volatile("global_store_dwordx4 %0, %1, off sc0 sc1 nt" :: "v"(p), "v"(v));
}

// exponent of |m| (normals: ilogbf), floored at -120, capped at 127
__device__ inline int exp_floor(float m) {
    int eb = (int)((__float_as_uint(m) >> 23) & 0xff);
    int e = (eb == 0) ? -120 : eb - 127;
    return max(-120, min(127, e));
}
// 2^k for k in [-126, 127] via exponent bits
__device__ inline float exp2i(int k) {
    return __uint_as_float((unsigned)(k + 127) << 23);
}

__global__ __launch_bounds__(256) void bq_pack(const float* __restrict__ x,
                                               unsigned int* __restrict__ j4,
                                               signed char* __restrict__ e8,
                                               float* __restrict__ partial,
                                               int n4) {
    const v4f* __restrict__ x4 = (const v4f*)x;
    const int tid = blockIdx.x * blockDim.x + threadIdx.x;
    const int T = gridDim.x * blockDim.x;
    float mblk = 0.0f;
    for (int i = tid; i < n4; i += T) {
        v4f v = __builtin_nontemporal_load(&x4[i]);  // x never re-read: bypass LLC
        float m = fmaxf(fmaxf(fabsf(v.x), fabsf(v.y)),
                        fmaxf(fabsf(v.z), fabsf(v.w)));
        mblk = fmaxf(mblk, m);
        const int e = exp_floor(m);
        const float s = exp2i(6 - e);          // 2^(6-e), finite since e >= -120
        int j0 = min(127, max(-128, (int)rintf(v.x * s)));
        int j1 = min(127, max(-128, (int)rintf(v.y * s)));
        int j2 = min(127, max(-128, (int)rintf(v.z * s)));
        int j3 = min(127, max(-128, (int)rintf(v.w * s)));
        j4[i] = (unsigned)(j0 & 0xff)         | ((unsigned)(j1 & 0xff) << 8) |
                ((unsigned)(j2 & 0xff) << 16) | ((unsigned)(j3 & 0xff) << 24);
        e8[i] = (signed char)e;
    }
    #pragma unroll
    for (int off = 32; off > 0; off >>= 1)
        mblk = fmaxf(mblk, __shfl_xor(mblk, off, 64));
    __shared__ float sm[4];
    if ((threadIdx.x & 63) == 0) sm[threadIdx.x >> 6] = mblk;
    __syncthreads();
    if (threadIdx.x == 0)
        partial[blockIdx.x] = fmaxf(fmaxf(sm[0], sm[1]), fmaxf(sm[2], sm[3]));
}

__global__ __launch_bounds__(256) void bq_emit(const unsigned int* __restrict__ j4,
                                               const signed char* __restrict__ e8,
                                               const float* __restrict__ partial,
                                               float* __restrict__ out,
                                               int n4) {
    float gm = 0.0f;
    #pragma unroll
    for (int k = 0; k < GRID1 / 256; ++k)
        gm = fmaxf(gm, partial[threadIdx.x + k * 256]);
    #pragma unroll
    for (int off = 32; off > 0; off >>= 1)
        gm = fmaxf(gm, __shfl_xor(gm, off, 64));
    __shared__ float sm[4];
    if ((threadIdx.x & 63) == 0) sm[threadIdx.x >> 6] = gm;
    __syncthreads();
    const float maxe = fmaxf(fmaxf(sm[0], sm[1]), fmaxf(sm[2], sm[3]));

    const int eg = exp_floor(maxe);            // all-zero input -> j==0 -> out 0 anyway
    const float invs = exp2i(eg - 6);          // 2^(eg-6), eg-6 in [-126, 121]
    v4f* __restrict__ o4 = (v4f*)out;

    const int tid = blockIdx.x * blockDim.x + threadIdx.x;
    const int T = gridDim.x * blockDim.x;
    for (int i = tid; i < n4; i += T) {
        const unsigned w = j4[i];
        const int ec = (int)e8[i];
        const float fs = ldexpf(1.0f, ec - eg);  // <=1; subnormal/0 ok for tiny ec-eg
        float f0 = (float)(int)(signed char)(w & 0xff);
        float f1 = (float)(int)(signed char)((w >> 8) & 0xff);
        float f2 = (float)(int)(signed char)((w >> 16) & 0xff);
        float f3 = (float)(int)(signed char)((w >> 24) & 0xff);
        v4f r;
        r.x = rintf(f0 * fs) * invs;   // f*fs exact; rne; |.|<=128 -> no clamp needed
        r.y = rintf(f1 * fs) * invs;
        r.z = rintf(f2 * fs) * invs;
        r.w = rintf(f3 * fs) * invs;
        store_stream(&o4[i], r);
    }
}

// ---------------- fallback: proven R4 two-pass ----------------

__global__ __launch_bounds__(256) void bq_absmax(const float* __restrict__ x,
                                                 float* __restrict__ partial,
                                                 int n) {
    const int n4 = n >> 2;
    const v4f* __restrict__ x4 = (const v4f*)x;
    int tid = blockIdx.x * blockDim.x + threadIdx.x;
    int stride = gridDim.x * blockDim.x;
    float m = 0.0f;
    for (int i = tid; i < n4; i += stride) {
        v4f v = x4[i];
        m = fmaxf(fmaxf(fabsf(v.x), fabsf(v.y)),
                  fmaxf(fmaxf(fabsf(v.z), fabsf(v.w)), m));
    }
    for (int i = (n4 << 2) + tid; i < n; i += stride) m = fmaxf(m, fabsf(x[i]));
    #pragma unroll
    for (int off = 32; off > 0; off >>= 1)
        m = fmaxf(m, __shfl_xor(m, off, 64));
    __shared__ float sm[4];
    if ((threadIdx.x & 63) == 0) sm[threadIdx.x >> 6] = m;
    __syncthreads();
    if (threadIdx.x == 0)
        partial[blockIdx.x] = fmaxf(fmaxf(sm[0], sm[1]), fmaxf(sm[2], sm[3]));
}

__global__ __launch_bounds__(256) void bq_quant(const float* __restrict__ x,
                                                float* __restrict__ out,
                                                const float* __restrict__ partial,
                                                int n) {
    float bm = 0.0f;
    #pragma unroll
    for (int k = 0; k < GRID1 / 256; ++k)
        bm = fmaxf(bm, partial[threadIdx.x + k * 256]);
    #pragma unroll
    for (int off = 32; off > 0; off >>= 1)
        bm = fmaxf(bm, __shfl_xor(bm, off, 64));
    __shared__ float sm[4];
    if ((threadIdx.x & 63) == 0) sm[threadIdx.x >> 6] = bm;
    __syncthreads();
    const float maxe = fmaxf(fmaxf(sm[0], sm[1]), fmaxf(sm[2], sm[3]));

    const int n4 = n >> 2;
    const v4f* __restrict__ x4 = (const v4f*)x;
    v4f* __restrict__ o4 = (v4f*)out;
    const int tid = blockIdx.x * blockDim.x + threadIdx.x;
    const int T = gridDim.x * blockDim.x;

    if (maxe == 0.0f) {
        for (int i = tid; i < n4; i += T) store_stream(&o4[i], x4[i]);
        for (int i = (n4 << 2) + tid; i < n; i += T) out[i] = x[i];
        return;
    }
    int e = ilogbf(maxe);
    e = max(-128, min(127, e));
    const float scale    = ldexpf(1.0f, -e + 6);
    const float invscale = ldexpf(1.0f, e - 6);
    for (int i = tid; i < n4; i += T) {
        v4f v = x4[i];
        float a = rintf(v.x * scale);
        float b = rintf(v.y * scale);
        float cc = rintf(v.z * scale);
        float d = rintf(v.w * scale);
        a  = fminf(fmaxf(a,  -128.0f), 127.0f);
        b  = fminf(fmaxf(b,  -128.0f), 127.0f);
        cc = fminf(fmaxf(cc, -128.0f), 127.0f);
        d  = fminf(fmaxf(d,  -128.0f), 127.0f);
        v4f r;
        r.x = a * invscale;
        r.y = b * invscale;
        r.z = cc * invscale;
        r.w = d * invscale;
        store_stream(&o4[i], r);
    }
    for (int i = (n4 << 2) + tid; i < n; i += T) {
        float a = rintf(x[i] * scale);
        a = fminf(fmaxf(a, -128.0f), 127.0f);
        out[i] = a * invscale;
    }
}

extern "C" void kernel_launch(void* const* d_in, const int* in_sizes, int n_in,
                              void* d_out, int out_size, void* d_ws, size_t ws_size,
                              hipStream_t stream) {
    const float* x = (const float*)d_in[0];
    float* out = (float*)d_out;
    int n = in_sizes[0];
    const int n4 = n >> 2;

    // ws layout: [partial: GRID1 floats][e8: n4 bytes][j4: n4 dwords]
    const size_t off_e8 = GRID1 * sizeof(float);
    const size_t off_j4 = (off_e8 + (size_t)n4 + 15) & ~(size_t)15;
    const size_t need   = off_j4 + (size_t)n4 * 4;

    float* partial = (float*)d_ws;

    if ((n & 3) == 0 && ws_size >= need) {
        signed char* e8  = (signed char*)d_ws + off_e8;
        unsigned int* j4 = (unsigned int*)((char*)d_ws + off_j4);
        hipLaunchKernelGGL(bq_pack, dim3(GRID1), dim3(256), 0, stream,
                           x, j4, e8, partial, n4);
        hipLaunchKernelGGL(bq_emit, dim3(GRID1), dim3(256), 0, stream,
                           j4, e8, partial, out, n4);
    } else {
        hipLaunchKernelGGL(bq_absmax, dim3(GRID1), dim3(256), 0, stream, x, partial, n);
        hipLaunchKernelGGL(bq_quant,  dim3(GRID1), dim3(256), 0, stream, x, out, partial, n);
    }
}

// Round 8
// 84.999 us; speedup vs baseline: 1.0755x; 1.0619x over previous
//
#include <hip/hip_runtime.h>
#include <math.h>

// SWALP global block-quantize via compressed int8 intermediate in d_ws:
//   k1: per-float4 group: e_c = floor(log2 max|v|) (bit-extract, floored at
//       -120), j = clamp(rne(v * 2^(6-e_c))) -> packed dword + int8 exponent.
//       Also per-block absmax -> partial[blockIdx].
//   k2: reduce partials -> e_g; out = rne(j * 2^(e_c-e_g)) * 2^(e_g-6).
//       j*2^(e_c-e_g) is exact (8-bit int x pow2), so error <= 1.5 quanta
//       (measured 1 quantum = 0.0625 < 0.10875 threshold).
// Traffic: 205R + 64W + 64R + 205W = 538 MB.
// R8 change vs R7: x read with PLAIN cached loads (A/B: nt-load suspected of
// the 6.0 vs 7.2 TB/s effective-BW gap). Output stores stay nt.

#define GRID1 2048

typedef float v4f __attribute__((ext_vector_type(4)));

__device__ inline void store_stream(v4f* p, v4f v) {
    asm volatile("global_store_dwordx4 %0, %1, off sc0 sc1 nt" :: "v"(p), "v"(v));
}

// exponent of |m| (normals: ilogbf), floored at -120, capped at 127
__device__ inline int exp_floor(float m) {
    int eb = (int)((__float_as_uint(m) >> 23) & 0xff);
    int e = (eb == 0) ? -120 : eb - 127;
    return max(-120, min(127, e));
}
// 2^k for k in [-126, 127] via exponent bits
__device__ inline float exp2i(int k) {
    return __uint_as_float((unsigned)(k + 127) << 23);
}

__global__ __launch_bounds__(256) void bq_pack(const float* __restrict__ x,
                                               unsigned int* __restrict__ j4,
                                               signed char* __restrict__ e8,
                                               float* __restrict__ partial,
                                               int n4) {
    const v4f* __restrict__ x4 = (const v4f*)x;
    const int tid = blockIdx.x * blockDim.x + threadIdx.x;
    const int T = gridDim.x * blockDim.x;
    float mblk = 0.0f;
    for (int i = tid; i < n4; i += T) {
        v4f v = x4[i];                          // plain cached load (R8 A/B)
        float m = fmaxf(fmaxf(fabsf(v.x), fabsf(v.y)),
                        fmaxf(fabsf(v.z), fabsf(v.w)));
        mblk = fmaxf(mblk, m);
        const int e = exp_floor(m);
        const float s = exp2i(6 - e);          // 2^(6-e), finite since e >= -120
        int j0 = min(127, max(-128, (int)rintf(v.x * s)));
        int j1 = min(127, max(-128, (int)rintf(v.y * s)));
        int j2 = min(127, max(-128, (int)rintf(v.z * s)));
        int j3 = min(127, max(-128, (int)rintf(v.w * s)));
        j4[i] = (unsigned)(j0 & 0xff)         | ((unsigned)(j1 & 0xff) << 8) |
                ((unsigned)(j2 & 0xff) << 16) | ((unsigned)(j3 & 0xff) << 24);
        e8[i] = (signed char)e;
    }
    #pragma unroll
    for (int off = 32; off > 0; off >>= 1)
        mblk = fmaxf(mblk, __shfl_xor(mblk, off, 64));
    __shared__ float sm[4];
    if ((threadIdx.x & 63) == 0) sm[threadIdx.x >> 6] = mblk;
    __syncthreads();
    if (threadIdx.x == 0)
        partial[blockIdx.x] = fmaxf(fmaxf(sm[0], sm[1]), fmaxf(sm[2], sm[3]));
}

__global__ __launch_bounds__(256) void bq_emit(const unsigned int* __restrict__ j4,
                                               const signed char* __restrict__ e8,
                                               const float* __restrict__ partial,
                                               float* __restrict__ out,
                                               int n4) {
    float gm = 0.0f;
    #pragma unroll
    for (int k = 0; k < GRID1 / 256; ++k)
        gm = fmaxf(gm, partial[threadIdx.x + k * 256]);
    #pragma unroll
    for (int off = 32; off > 0; off >>= 1)
        gm = fmaxf(gm, __shfl_xor(gm, off, 64));
    __shared__ float sm[4];
    if ((threadIdx.x & 63) == 0) sm[threadIdx.x >> 6] = gm;
    __syncthreads();
    const float maxe = fmaxf(fmaxf(sm[0], sm[1]), fmaxf(sm[2], sm[3]));

    const int eg = exp_floor(maxe);            // all-zero input -> j==0 -> out 0 anyway
    const float invs = exp2i(eg - 6);          // 2^(eg-6), eg-6 in [-126, 121]
    v4f* __restrict__ o4 = (v4f*)out;

    const int tid = blockIdx.x * blockDim.x + threadIdx.x;
    const int T = gridDim.x * blockDim.x;
    for (int i = tid; i < n4; i += T) {
        const unsigned w = j4[i];
        const int ec = (int)e8[i];
        const float fs = ldexpf(1.0f, ec - eg);  // <=1; handles large negative ec-eg
        float f0 = (float)(int)(signed char)(w & 0xff);
        float f1 = (float)(int)(signed char)((w >> 8) & 0xff);
        float f2 = (float)(int)(signed char)((w >> 16) & 0xff);
        float f3 = (float)(int)(signed char)((w >> 24) & 0xff);
        v4f r;
        r.x = rintf(f0 * fs) * invs;   // f*fs exact; rne; result exact pow2 multiple
        r.y = rintf(f1 * fs) * invs;
        r.z = rintf(f2 * fs) * invs;
        r.w = rintf(f3 * fs) * invs;
        store_stream(&o4[i], r);
    }
}

// ---------------- fallback: proven R4 two-pass ----------------

__global__ __launch_bounds__(256) void bq_absmax(const float* __restrict__ x,
                                                 float* __restrict__ partial,
                                                 int n) {
    const int n4 = n >> 2;
    const v4f* __restrict__ x4 = (const v4f*)x;
    int tid = blockIdx.x * blockDim.x + threadIdx.x;
    int stride = gridDim.x * blockDim.x;
    float m = 0.0f;
    for (int i = tid; i < n4; i += stride) {
        v4f v = x4[i];
        m = fmaxf(fmaxf(fabsf(v.x), fabsf(v.y)),
                  fmaxf(fmaxf(fabsf(v.z), fabsf(v.w)), m));
    }
    for (int i = (n4 << 2) + tid; i < n; i += stride) m = fmaxf(m, fabsf(x[i]));
    #pragma unroll
    for (int off = 32; off > 0; off >>= 1)
        m = fmaxf(m, __shfl_xor(m, off, 64));
    __shared__ float sm[4];
    if ((threadIdx.x & 63) == 0) sm[threadIdx.x >> 6] = m;
    __syncthreads();
    if (threadIdx.x == 0)
        partial[blockIdx.x] = fmaxf(fmaxf(sm[0], sm[1]), fmaxf(sm[2], sm[3]));
}

__global__ __launch_bounds__(256) void bq_quant(const float* __restrict__ x,
                                                float* __restrict__ out,
                                                const float* __restrict__ partial,
                                                int n) {
    float bm = 0.0f;
    #pragma unroll
    for (int k = 0; k < GRID1 / 256; ++k)
        bm = fmaxf(bm, partial[threadIdx.x + k * 256]);
    #pragma unroll
    for (int off = 32; off > 0; off >>= 1)
        bm = fmaxf(bm, __shfl_xor(bm, off, 64));
    __shared__ float sm[4];
    if ((threadIdx.x & 63) == 0) sm[threadIdx.x >> 6] = bm;
    __syncthreads();
    const float maxe = fmaxf(fmaxf(sm[0], sm[1]), fmaxf(sm[2], sm[3]));

    const int n4 = n >> 2;
    const v4f* __restrict__ x4 = (const v4f*)x;
    v4f* __restrict__ o4 = (v4f*)out;
    const int tid = blockIdx.x * blockDim.x + threadIdx.x;
    const int T = gridDim.x * blockDim.x;

    if (maxe == 0.0f) {
        for (int i = tid; i < n4; i += T) store_stream(&o4[i], x4[i]);
        for (int i = (n4 << 2) + tid; i < n; i += T) out[i] = x[i];
        return;
    }
    int e = ilogbf(maxe);
    e = max(-128, min(127, e));
    const float scale    = ldexpf(1.0f, -e + 6);
    const float invscale = ldexpf(1.0f, e - 6);
    for (int i = tid; i < n4; i += T) {
        v4f v = x4[i];
        float a = rintf(v.x * scale);
        float b = rintf(v.y * scale);
        float cc = rintf(v.z * scale);
        float d = rintf(v.w * scale);
        a  = fminf(fmaxf(a,  -128.0f), 127.0f);
        b  = fminf(fmaxf(b,  -128.0f), 127.0f);
        cc = fminf(fmaxf(cc, -128.0f), 127.0f);
        d  = fminf(fmaxf(d,  -128.0f), 127.0f);
        v4f r;
        r.x = a * invscale;
        r.y = b * invscale;
        r.z = cc * invscale;
        r.w = d * invscale;
        store_stream(&o4[i], r);
    }
    for (int i = (n4 << 2) + tid; i < n; i += T) {
        float a = rintf(x[i] * scale);
        a = fminf(fmaxf(a, -128.0f), 127.0f);
        out[i] = a * invscale;
    }
}

extern "C" void kernel_launch(void* const* d_in, const int* in_sizes, int n_in,
                              void* d_out, int out_size, void* d_ws, size_t ws_size,
                              hipStream_t stream) {
    const float* x = (const float*)d_in[0];
    float* out = (float*)d_out;
    int n = in_sizes[0];
    const int n4 = n >> 2;

    // ws layout: [partial: GRID1 floats][e8: n4 bytes][j4: n4 dwords]
    const size_t off_e8 = GRID1 * sizeof(float);
    const size_t off_j4 = (off_e8 + (size_t)n4 + 15) & ~(size_t)15;
    const size_t need   = off_j4 + (size_t)n4 * 4;

    float* partial = (float*)d_ws;

    if ((n & 3) == 0 && ws_size >= need) {
        signed char* e8  = (signed char*)d_ws + off_e8;
        unsigned int* j4 = (unsigned int*)((char*)d_ws + off_j4);
        hipLaunchKernelGGL(bq_pack, dim3(GRID1), dim3(256), 0, stream,
                           x, j4, e8, partial, n4);
        hipLaunchKernelGGL(bq_emit, dim3(GRID1), dim3(256), 0, stream,
                           j4, e8, partial, out, n4);
    } else {
        hipLaunchKernelGGL(bq_absmax, dim3(GRID1), dim3(256), 0, stream, x, partial, n);
        hipLaunchKernelGGL(bq_quant,  dim3(GRID1), dim3(256), 0, stream, x, out, partial, n);
    }
}

// Round 9
// 80.427 us; speedup vs baseline: 1.1367x; 1.0568x over previous
//
#include <hip/hip_runtime.h>
#include <math.h>

// SWALP global block-quantize, chunked int8 intermediate (R9):
//   k1: each thread buffers CH=7 float4 (28 elems, wave-interleaved positions),
//       e_c = floor(log2 chunkmax) (floored at -120), j = clamp(rne(v*2^(6-e_c)))
//       -> 7 packed dwords + ONE int8 exponent per 28 elems. Block absmax -> partial.
//   k2: reduce partials -> e_g; out = rne(j * 2^(e_c-e_g)) * 2^(e_g-6), nt stores.
//   Error <= 1 output quantum (0.0625 < 0.10875): e_c<=e_g, j*2^(e_c-e_g) exact,
//   both int results differ by <=1 after RNE.
// Traffic: 205.5R + 53.2W + 53.2R + 205.5W = 517 MB (R8: 539; R4: 616).
// Sideband is cached (53 MB << 256 MB LLC) for k2 re-read; only `out` is nt.

#define NB 1792                 // 7 blocks/CU
#define NT 256
#define TT (NB * NT)            // 458752 threads
#define CH 7                    // float4 per chunk
#define ITERS 4                 // TT * CH * ITERS == n4 == 12,845,056 exactly
#define GRID1 2048              // fallback grid

typedef float v4f __attribute__((ext_vector_type(4)));

__device__ inline void store_stream(v4f* p, v4f v) {
    asm volatile("global_store_dwordx4 %0, %1, off sc0 sc1 nt" :: "v"(p), "v"(v));
}
__device__ inline int exp_floor(float m) {          // floor(log2|m|), floored at -120
    int eb = (int)((__float_as_uint(m) >> 23) & 0xff);
    int e = (eb == 0) ? -120 : eb - 127;
    return max(-120, min(127, e));
}
__device__ inline float exp2i(int k) {              // 2^k, k in [-126,127]
    return __uint_as_float((unsigned)(k + 127) << 23);
}

__global__ __launch_bounds__(NT) void bq_pack7(const float* __restrict__ x,
                                               unsigned int* __restrict__ j4,
                                               signed char* __restrict__ e8,
                                               float* __restrict__ partial) {
    const v4f* __restrict__ x4 = (const v4f*)x;
    const int gtid = blockIdx.x * NT + threadIdx.x;
    float mblk = 0.0f;

    for (int it = 0; it < ITERS; ++it) {
        v4f v[CH];
        #pragma unroll
        for (int k = 0; k < CH; ++k)
            v[k] = x4[(size_t)(it * CH + k) * TT + gtid];

        float m = 0.0f;
        #pragma unroll
        for (int k = 0; k < CH; ++k)
            m = fmaxf(m, fmaxf(fmaxf(fabsf(v[k].x), fabsf(v[k].y)),
                               fmaxf(fabsf(v[k].z), fabsf(v[k].w))));
        mblk = fmaxf(mblk, m);

        const int e = exp_floor(m);
        const float s = exp2i(6 - e);       // finite: e >= -120
        #pragma unroll
        for (int k = 0; k < CH; ++k) {
            int j0 = min(127, max(-128, (int)rintf(v[k].x * s)));
            int j1 = min(127, max(-128, (int)rintf(v[k].y * s)));
            int j2 = min(127, max(-128, (int)rintf(v[k].z * s)));
            int j3 = min(127, max(-128, (int)rintf(v[k].w * s)));
            j4[(size_t)(it * CH + k) * TT + gtid] =
                (unsigned)(j0 & 0xff)         | ((unsigned)(j1 & 0xff) << 8) |
                ((unsigned)(j2 & 0xff) << 16) | ((unsigned)(j3 & 0xff) << 24);
        }
        e8[(size_t)it * TT + gtid] = (signed char)e;
    }

    #pragma unroll
    for (int off = 32; off > 0; off >>= 1)
        mblk = fmaxf(mblk, __shfl_xor(mblk, off, 64));
    __shared__ float sm[4];
    if ((threadIdx.x & 63) == 0) sm[threadIdx.x >> 6] = mblk;
    __syncthreads();
    if (threadIdx.x == 0)
        partial[blockIdx.x] = fmaxf(fmaxf(sm[0], sm[1]), fmaxf(sm[2], sm[3]));
}

__global__ __launch_bounds__(NT) void bq_emit7(const unsigned int* __restrict__ j4,
                                               const signed char* __restrict__ e8,
                                               const float* __restrict__ partial,
                                               float* __restrict__ out) {
    float gm = 0.0f;
    #pragma unroll
    for (int k = 0; k < NB / NT; ++k)
        gm = fmaxf(gm, partial[threadIdx.x + k * NT]);
    #pragma unroll
    for (int off = 32; off > 0; off >>= 1)
        gm = fmaxf(gm, __shfl_xor(gm, off, 64));
    __shared__ float sm[4];
    if ((threadIdx.x & 63) == 0) sm[threadIdx.x >> 6] = gm;
    __syncthreads();
    const float maxe = fmaxf(fmaxf(sm[0], sm[1]), fmaxf(sm[2], sm[3]));

    const int eg = exp_floor(maxe);
    const float invs = exp2i(eg - 6);       // eg-6 in [-126,121]
    v4f* __restrict__ o4 = (v4f*)out;
    const int gtid = blockIdx.x * NT + threadIdx.x;

    for (int it = 0; it < ITERS; ++it) {
        const int ec = (int)e8[(size_t)it * TT + gtid];
        const float fs = ldexpf(1.0f, ec - eg);   // <=1, safe for any ec-eg
        #pragma unroll
        for (int k = 0; k < CH; ++k) {
            const unsigned w = j4[(size_t)(it * CH + k) * TT + gtid];
            float f0 = (float)(int)(signed char)(w & 0xff);
            float f1 = (float)(int)(signed char)((w >> 8) & 0xff);
            float f2 = (float)(int)(signed char)((w >> 16) & 0xff);
            float f3 = (float)(int)(signed char)((w >> 24) & 0xff);
            v4f r;
            r.x = rintf(f0 * fs) * invs;   // f*fs exact (8-bit int x pow2)
            r.y = rintf(f1 * fs) * invs;
            r.z = rintf(f2 * fs) * invs;
            r.w = rintf(f3 * fs) * invs;
            store_stream(&o4[(size_t)(it * CH + k) * TT + gtid], r);
        }
    }
}

// ---------------- fallback: proven R4 two-pass ----------------

__global__ __launch_bounds__(256) void bq_absmax(const float* __restrict__ x,
                                                 float* __restrict__ partial,
                                                 int n) {
    const int n4 = n >> 2;
    const v4f* __restrict__ x4 = (const v4f*)x;
    int tid = blockIdx.x * blockDim.x + threadIdx.x;
    int stride = gridDim.x * blockDim.x;
    float m = 0.0f;
    for (int i = tid; i < n4; i += stride) {
        v4f v = x4[i];
        m = fmaxf(fmaxf(fabsf(v.x), fabsf(v.y)),
                  fmaxf(fmaxf(fabsf(v.z), fabsf(v.w)), m));
    }
    for (int i = (n4 << 2) + tid; i < n; i += stride) m = fmaxf(m, fabsf(x[i]));
    #pragma unroll
    for (int off = 32; off > 0; off >>= 1)
        m = fmaxf(m, __shfl_xor(m, off, 64));
    __shared__ float sm[4];
    if ((threadIdx.x & 63) == 0) sm[threadIdx.x >> 6] = m;
    __syncthreads();
    if (threadIdx.x == 0)
        partial[blockIdx.x] = fmaxf(fmaxf(sm[0], sm[1]), fmaxf(sm[2], sm[3]));
}

__global__ __launch_bounds__(256) void bq_quant(const float* __restrict__ x,
                                                float* __restrict__ out,
                                                const float* __restrict__ partial,
                                                int n) {
    float bm = 0.0f;
    #pragma unroll
    for (int k = 0; k < GRID1 / 256; ++k)
        bm = fmaxf(bm, partial[threadIdx.x + k * 256]);
    #pragma unroll
    for (int off = 32; off > 0; off >>= 1)
        bm = fmaxf(bm, __shfl_xor(bm, off, 64));
    __shared__ float sm[4];
    if ((threadIdx.x & 63) == 0) sm[threadIdx.x >> 6] = bm;
    __syncthreads();
    const float maxe = fmaxf(fmaxf(sm[0], sm[1]), fmaxf(sm[2], sm[3]));

    const int n4 = n >> 2;
    const v4f* __restrict__ x4 = (const v4f*)x;
    v4f* __restrict__ o4 = (v4f*)out;
    const int tid = blockIdx.x * blockDim.x + threadIdx.x;
    const int T = gridDim.x * blockDim.x;

    if (maxe == 0.0f) {
        for (int i = tid; i < n4; i += T) store_stream(&o4[i], x4[i]);
        for (int i = (n4 << 2) + tid; i < n; i += T) out[i] = x[i];
        return;
    }
    int e = ilogbf(maxe);
    e = max(-128, min(127, e));
    const float scale    = ldexpf(1.0f, -e + 6);
    const float invscale = ldexpf(1.0f, e - 6);
    for (int i = tid; i < n4; i += T) {
        v4f v = x4[i];
        float a = rintf(v.x * scale);
        float b = rintf(v.y * scale);
        float cc = rintf(v.z * scale);
        float d = rintf(v.w * scale);
        a  = fminf(fmaxf(a,  -128.0f), 127.0f);
        b  = fminf(fmaxf(b,  -128.0f), 127.0f);
        cc = fminf(fmaxf(cc, -128.0f), 127.0f);
        d  = fminf(fmaxf(d,  -128.0f), 127.0f);
        v4f r;
        r.x = a * invscale;
        r.y = b * invscale;
        r.z = cc * invscale;
        r.w = d * invscale;
        store_stream(&o4[i], r);
    }
    for (int i = (n4 << 2) + tid; i < n; i += T) {
        float a = rintf(x[i] * scale);
        a = fminf(fmaxf(a, -128.0f), 127.0f);
        out[i] = a * invscale;
    }
}

extern "C" void kernel_launch(void* const* d_in, const int* in_sizes, int n_in,
                              void* d_out, int out_size, void* d_ws, size_t ws_size,
                              hipStream_t stream) {
    const float* x = (const float*)d_in[0];
    float* out = (float*)d_out;
    int n = in_sizes[0];
    const int n4 = n >> 2;

    // ws layout: [partial: NB floats][e8: ITERS*TT bytes][j4: n4 dwords]
    const size_t off_e8 = ((size_t)NB * 4 + 15) & ~(size_t)15;
    const size_t off_j4 = (off_e8 + (size_t)ITERS * TT + 15) & ~(size_t)15;
    const size_t need   = off_j4 + (size_t)n4 * 4;

    float* partial = (float*)d_ws;

    if ((n & 3) == 0 && n4 == TT * CH * ITERS && ws_size >= need) {
        signed char* e8  = (signed char*)d_ws + off_e8;
        unsigned int* j4 = (unsigned int*)((char*)d_ws + off_j4);
        hipLaunchKernelGGL(bq_pack7, dim3(NB), dim3(NT), 0, stream, x, j4, e8, partial);
        hipLaunchKernelGGL(bq_emit7, dim3(NB), dim3(NT), 0, stream, j4, e8, partial, out);
    } else {
        hipLaunchKernelGGL(bq_absmax, dim3(GRID1), dim3(256), 0, stream, x, partial, n);
        hipLaunchKernelGGL(bq_quant,  dim3(GRID1), dim3(256), 0, stream, x, out, partial, n);
    }
}

// Round 11
// 76.344 us; speedup vs baseline: 1.1975x; 1.0535x over previous
//
#include <hip/hip_runtime.h>
#include <math.h>

// SWALP global block-quantize, deterministic speculate+fix (R11 = R10 with
// builtin nt stores instead of inline asm — R10's absmax=75.75 was impossible
// under store semantics (|out| <= 8 provably), implicating the 28-deep
// unrolled asm store codegen; __builtin_nontemporal_store was proven in R3):
//   k1: block register-buffers its 28672-elem slice (28 v4f/thread), block
//       max -> partial[b], quantize with BLOCK exponent e_c, nt-store to out.
//       Bit-exact wherever e_c == e_g (~84% of blocks for N(0,1)).
//   k2: reduce partial -> e_g; blocks with e_c == e_g exit (uniform branch);
//       mismatched blocks requantize FROM X with e_g -> single rounding ->
//       bit-exact. Deterministic (pure function of input).
// Traffic: 205.5R + 205.5W + ~16% * 67 MB = ~478 MB (R9: 517).

#define NB 1792                 // blocks; NB*NT*CH*4 == n exactly
#define NT 256
#define CH 28                   // float4 per thread; slice = NT*CH = 7168 float4
#define GRID1 2048              // fallback grid

typedef float v4f __attribute__((ext_vector_type(4)));

__device__ inline int exp_floor(float m) {          // floor(log2|m|), floored at -120
    int eb = (int)((__float_as_uint(m) >> 23) & 0xff);
    int e = (eb == 0) ? -120 : eb - 127;
    return max(-120, min(127, e));
}
__device__ inline float exp2i(int k) {              // 2^k, k in [-126,127]
    return __uint_as_float((unsigned)(k + 127) << 23);
}
__device__ inline v4f quant4(v4f v, float s, float inv) {
    float a = fminf(fmaxf(rintf(v.x * s), -128.0f), 127.0f);
    float b = fminf(fmaxf(rintf(v.y * s), -128.0f), 127.0f);
    float c = fminf(fmaxf(rintf(v.z * s), -128.0f), 127.0f);
    float d = fminf(fmaxf(rintf(v.w * s), -128.0f), 127.0f);
    v4f r;
    r.x = a * inv; r.y = b * inv; r.z = c * inv; r.w = d * inv;
    return r;
}

__global__ __launch_bounds__(NT) void bq_spec(const float* __restrict__ x,
                                              float* __restrict__ out,
                                              float* __restrict__ partial) {
    const v4f* __restrict__ x4 = (const v4f*)x + (size_t)blockIdx.x * (NT * CH);
    v4f* __restrict__ o4 = (v4f*)out + (size_t)blockIdx.x * (NT * CH);
    const int t = threadIdx.x;

    v4f v[CH];
    #pragma unroll
    for (int k = 0; k < CH; ++k)
        v[k] = x4[k * NT + t];

    float m = 0.0f;
    #pragma unroll
    for (int k = 0; k < CH; ++k)
        m = fmaxf(m, fmaxf(fmaxf(fabsf(v[k].x), fabsf(v[k].y)),
                           fmaxf(fabsf(v[k].z), fabsf(v[k].w))));
    #pragma unroll
    for (int off = 32; off > 0; off >>= 1)
        m = fmaxf(m, __shfl_xor(m, off, 64));
    __shared__ float sm[4];
    if ((t & 63) == 0) sm[t >> 6] = m;
    __syncthreads();
    const float mb = fmaxf(fmaxf(sm[0], sm[1]), fmaxf(sm[2], sm[3]));
    if (t == 0) partial[blockIdx.x] = mb;

    const int e = exp_floor(mb);
    const float s = exp2i(6 - e), inv = exp2i(e - 6);
    #pragma unroll
    for (int k = 0; k < CH; ++k)
        __builtin_nontemporal_store(quant4(v[k], s, inv), &o4[k * NT + t]);
}

__global__ __launch_bounds__(NT) void bq_fix(const float* __restrict__ x,
                                             float* __restrict__ out,
                                             const float* __restrict__ partial) {
    const int t = threadIdx.x;
    float g = 0.0f;
    #pragma unroll
    for (int k = 0; k < NB / NT; ++k)
        g = fmaxf(g, partial[t + k * NT]);
    #pragma unroll
    for (int off = 32; off > 0; off >>= 1)
        g = fmaxf(g, __shfl_xor(g, off, 64));
    __shared__ float sm[4];
    if ((t & 63) == 0) sm[t >> 6] = g;
    __syncthreads();
    const float mg = fmaxf(fmaxf(sm[0], sm[1]), fmaxf(sm[2], sm[3]));
    const int eg = exp_floor(mg);

    const float mb = partial[blockIdx.x];       // uniform broadcast load
    if (exp_floor(mb) == eg) return;            // block-uniform early exit (~84%)

    const v4f* __restrict__ x4 = (const v4f*)x + (size_t)blockIdx.x * (NT * CH);
    v4f* __restrict__ o4 = (v4f*)out + (size_t)blockIdx.x * (NT * CH);
    const float s = exp2i(6 - eg), inv = exp2i(eg - 6);
    #pragma unroll
    for (int k = 0; k < CH; ++k)
        __builtin_nontemporal_store(quant4(x4[k * NT + t], s, inv), &o4[k * NT + t]);
}

// ---------------- fallback: proven R4 two-pass ----------------

__global__ __launch_bounds__(256) void bq_absmax(const float* __restrict__ x,
                                                 float* __restrict__ partial,
                                                 int n) {
    const int n4 = n >> 2;
    const v4f* __restrict__ x4 = (const v4f*)x;
    int tid = blockIdx.x * blockDim.x + threadIdx.x;
    int stride = gridDim.x * blockDim.x;
    float m = 0.0f;
    for (int i = tid; i < n4; i += stride) {
        v4f v = x4[i];
        m = fmaxf(fmaxf(fabsf(v.x), fabsf(v.y)),
                  fmaxf(fmaxf(fabsf(v.z), fabsf(v.w)), m));
    }
    for (int i = (n4 << 2) + tid; i < n; i += stride) m = fmaxf(m, fabsf(x[i]));
    #pragma unroll
    for (int off = 32; off > 0; off >>= 1)
        m = fmaxf(m, __shfl_xor(m, off, 64));
    __shared__ float sm[4];
    if ((threadIdx.x & 63) == 0) sm[threadIdx.x >> 6] = m;
    __syncthreads();
    if (threadIdx.x == 0)
        partial[blockIdx.x] = fmaxf(fmaxf(sm[0], sm[1]), fmaxf(sm[2], sm[3]));
}

__global__ __launch_bounds__(256) void bq_quant(const float* __restrict__ x,
                                                float* __restrict__ out,
                                                const float* __restrict__ partial,
                                                int n) {
    float bm = 0.0f;
    #pragma unroll
    for (int k = 0; k < GRID1 / 256; ++k)
        bm = fmaxf(bm, partial[threadIdx.x + k * 256]);
    #pragma unroll
    for (int off = 32; off > 0; off >>= 1)
        bm = fmaxf(bm, __shfl_xor(bm, off, 64));
    __shared__ float sm[4];
    if ((threadIdx.x & 63) == 0) sm[threadIdx.x >> 6] = bm;
    __syncthreads();
    const float maxe = fmaxf(fmaxf(sm[0], sm[1]), fmaxf(sm[2], sm[3]));

    const int n4 = n >> 2;
    const v4f* __restrict__ x4 = (const v4f*)x;
    v4f* __restrict__ o4 = (v4f*)out;
    const int tid = blockIdx.x * blockDim.x + threadIdx.x;
    const int T = gridDim.x * blockDim.x;

    if (maxe == 0.0f) {
        for (int i = tid; i < n4; i += T)
            __builtin_nontemporal_store(x4[i], &o4[i]);
        for (int i = (n4 << 2) + tid; i < n; i += T) out[i] = x[i];
        return;
    }
    int e = ilogbf(maxe);
    e = max(-128, min(127, e));
    const float scale    = ldexpf(1.0f, -e + 6);
    const float invscale = ldexpf(1.0f, e - 6);
    for (int i = tid; i < n4; i += T)
        __builtin_nontemporal_store(quant4(x4[i], scale, invscale), &o4[i]);
    for (int i = (n4 << 2) + tid; i < n; i += T) {
        float a = rintf(x[i] * scale);
        a = fminf(fmaxf(a, -128.0f), 127.0f);
        out[i] = a * invscale;
    }
}

extern "C" void kernel_launch(void* const* d_in, const int* in_sizes, int n_in,
                              void* d_out, int out_size, void* d_ws, size_t ws_size,
                              hipStream_t stream) {
    const float* x = (const float*)d_in[0];
    float* out = (float*)d_out;
    float* partial = (float*)d_ws;   // NB floats (fallback uses GRID1 floats)
    int n = in_sizes[0];

    const long need_n = (long)NB * NT * CH * 4;
    if ((long)n == need_n && ws_size >= (size_t)(GRID1 > NB ? GRID1 : NB) * 4) {
        hipLaunchKernelGGL(bq_spec, dim3(NB), dim3(NT), 0, stream, x, out, partial);
        hipLaunchKernelGGL(bq_fix,  dim3(NB), dim3(NT), 0, stream, x, out, partial);
    } else {
        hipLaunchKernelGGL(bq_absmax, dim3(GRID1), dim3(256), 0, stream, x, partial, n);
        hipLaunchKernelGGL(bq_quant,  dim3(GRID1), dim3(256), 0, stream, x, out, partial, n);
    }
}